// Round 3
// baseline (245.117 us; speedup 1.0000x reference)
//
#include <hip/hip_runtime.h>
#include <math.h>

// Problem constants
#define B 2
#define N 8192
#define M 8192
#define NPTS (B*N)
#define VD 64
#define VH 128
#define VW 128
#define VVOX (VD*VH*VW)         // 1048576 voxels per batch
#define DHH 512
#define DWW 512
#define DPIX (DHH*DWW)

// Workspace layout (float indices)
#define OFF_PACK_P 0                       // NPTS float4 (x,y,z,|p|^2)
#define OFF_PACK_G (NPTS*4)
#define OFF_MIN_P  (NPTS*8)                // NPTS floats
#define OFF_MIN_G  (NPTS*8 + NPTS)
#define OFF_ACC    (NPTS*8 + 2*NPTS)       // 16 accumulators
#define OFF_WH_P   (OFF_ACC + 16)          // B*VVOX floats: (w,h)-eroded pred
#define OFF_WH_G   (OFF_WH_P + B*VVOX)     // B*VVOX floats: (w,h)-eroded gt
// acc: [0,1]=inter_b [2,3]=psum_b [4,5]=gsum_b [6,7]=sum_g_b [8,9]=sum_g2_b
//      [10]=gradx [11]=grady [12]=mask_num [13]=mask_den [14]=sum_minP [15]=sum_minG

__device__ __forceinline__ float blockSum(float v, volatile float* sm) {
    #pragma unroll
    for (int o = 32; o > 0; o >>= 1) v += __shfl_down(v, o, 64);
    int lane = threadIdx.x & 63, wid = threadIdx.x >> 6;
    __syncthreads();
    if (lane == 0) sm[wid] = v;
    __syncthreads();
    return sm[0] + sm[1] + sm[2] + sm[3];
}

__device__ __forceinline__ float min3f(float a, float b, float c) {
    return fminf(a, fminf(b, c));
}

// ---- init (+inf mins, zero acc) fused with point packing
__global__ __launch_bounds__(256) void k_init_pack(const float* __restrict__ pc,
                                                   const float* __restrict__ gp,
                                                   float* ws) {
    int i = blockIdx.x * 256 + threadIdx.x;   // [0, 32768)
    ((unsigned int*)(ws + OFF_MIN_P))[i] = 0x7F800000u; // +inf over both min arrays
    if (i < 16) ws[OFF_ACC + i] = 0.f;
    if (i < NPTS) {
        float x = pc[3*i], y = pc[3*i+1], z = pc[3*i+2];
        ((float4*)(ws + OFF_PACK_P))[i] = make_float4(x, y, z, x*x + y*y + z*z);
        x = gp[3*i]; y = gp[3*i+1]; z = gp[3*i+2];
        ((float4*)(ws + OFF_PACK_G))[i] = make_float4(x, y, z, x*x + y*y + z*z);
    }
}

// ---- chamfer, register-tiled: 8 queries/thread, targets staged in LDS.
#define QT 8
#define SEGS 32
#define TSEG (M/SEGS)   // 256 targets per block, 4KB LDS
__global__ __launch_bounds__(256) void k_chamfer(float* ws) {
    __shared__ float4 tt[TSEG];
    const float4* packP = (const float4*)(ws + OFF_PACK_P);
    const float4* packG = (const float4*)(ws + OFF_PACK_G);
    unsigned int bid = blockIdx.x;
    int dir  = bid >> 8;
    int rem  = bid & 255;
    int seg  = rem >> 3;
    int qblk = rem & 7;
    const float4* Q = dir ? packG : packP;
    const float4* T = dir ? packP : packG;
    unsigned int* minArr = (unsigned int*)(ws + (dir ? OFF_MIN_G : OFF_MIN_P));

    int qbase = qblk * (256*QT);
    int b = qbase >> 13;

    tt[threadIdx.x] = T[b*M + seg*TSEG + threadIdx.x];

    float nx[QT], ny[QT], nz[QT], q2[QT], dmin[QT];
    #pragma unroll
    for (int k = 0; k < QT; ++k) {
        float4 qv = Q[qbase + k*256 + threadIdx.x];
        nx[k] = -2.f*qv.x; ny[k] = -2.f*qv.y; nz[k] = -2.f*qv.z;
        q2[k] = qv.w; dmin[k] = INFINITY;
    }
    __syncthreads();

    #pragma unroll 4
    for (int j = 0; j < TSEG; ++j) {
        float4 tv = tt[j];
        #pragma unroll
        for (int k = 0; k < QT; ++k) {
            float d = fmaf(tv.x, nx[k], fmaf(tv.y, ny[k], fmaf(tv.z, nz[k], tv.w)));
            dmin[k] = fminf(dmin[k], d);
        }
    }
    #pragma unroll
    for (int k = 0; k < QT; ++k)
        atomicMin(minArr + qbase + k*256 + threadIdx.x,
                  __float_as_uint(dmin[k] + q2[k]));
}

// ---- erodeA: separable (w,h) 3x3 min for BOTH volumes.
// Rows = B*VD*VH = 16384; 8 rows/block x 32 float4-quads. 2048 blocks.
// Index clamping == SAME(+inf) padding for min (duplicates are idempotent).
__global__ __launch_bounds__(256) void k_erodeA(const float* __restrict__ pv,
                                                const float* __restrict__ gv,
                                                float* ws) {
    int r0 = blockIdx.x * 8 + (threadIdx.x >> 5);  // global row
    int q  = threadIdx.x & 31;
    int w  = q * 4;
    int b  = r0 >> 13;
    int rb = r0 & 8191;
    int d  = rb >> 7;
    int h  = rb & 127;
    int rowOff = b*VVOX + d*(VH*VW) + h*VW;
    int up = (h > 0)   ? -VW : 0;
    int dn = (h < 127) ?  VW : 0;

    float4 om[2];
    const float* vols[2] = {pv, gv};
    #pragma unroll
    for (int a = 0; a < 2; ++a) {
        const float* row = vols[a] + rowOff;
        float4 acc = make_float4(INFINITY, INFINITY, INFINITY, INFINITY);
        #pragma unroll
        for (int rr = 0; rr < 3; ++rr) {
            const float* rw = row + (rr == 0 ? up : (rr == 2 ? dn : 0));
            float4 c = *(const float4*)(rw + w);
            float l = (q > 0)  ? rw[w-1] : c.x;
            float r = (q < 31) ? rw[w+4] : c.w;
            acc.x = fminf(acc.x, min3f(l,   c.x, c.y));
            acc.y = fminf(acc.y, min3f(c.x, c.y, c.z));
            acc.z = fminf(acc.z, min3f(c.y, c.z, c.w));
            acc.w = fminf(acc.w, min3f(c.z, c.w, r));
        }
        om[a] = acc;
    }
    ((float4*)(ws + OFF_WH_P + rowOff))[q] = om[0];
    ((float4*)(ws + OFF_WH_G + rowOff))[q] = om[1];
}

// ---- erodeB: d-direction min + sigmoid + clDice partial sums.
__global__ __launch_bounds__(256) void k_erodeB(float* ws) {
    __shared__ float sm[4];
    int r0 = blockIdx.x * 8 + (threadIdx.x >> 5);
    int q  = threadIdx.x & 31;
    int b  = r0 >> 13;                 // uniform per block (8 | 8192)
    int rb = r0 & 8191;
    int d  = rb >> 7;
    int h  = rb & 127;
    int rowOff = b*VVOX + d*(VH*VW) + h*VW;
    int up = (d > 0)  ? -(VH*VW) : 0;
    int dn = (d < 63) ?  (VH*VW) : 0;

    const float* whP = ws + OFF_WH_P + rowOff;
    const float* whG = ws + OFF_WH_G + rowOff;
    float4 p0 = *(const float4*)(whP + up + 4*q);
    float4 p1 = *(const float4*)(whP + 4*q);
    float4 p2 = *(const float4*)(whP + dn + 4*q);
    float4 g0 = *(const float4*)(whG + up + 4*q);
    float4 g1 = *(const float4*)(whG + 4*q);
    float4 g2 = *(const float4*)(whG + dn + 4*q);
    float4 mp = make_float4(min3f(p0.x,p1.x,p2.x), min3f(p0.y,p1.y,p2.y),
                            min3f(p0.z,p1.z,p2.z), min3f(p0.w,p1.w,p2.w));
    float4 mg = make_float4(min3f(g0.x,g1.x,g2.x), min3f(g0.y,g1.y,g2.y),
                            min3f(g0.z,g1.z,g2.z), min3f(g0.w,g1.w,g2.w));
    float4 ps = make_float4(1.f/(1.f+__expf(-mp.x)), 1.f/(1.f+__expf(-mp.y)),
                            1.f/(1.f+__expf(-mp.z)), 1.f/(1.f+__expf(-mp.w)));
    float li = ps.x*mg.x + ps.y*mg.y + ps.z*mg.z + ps.w*mg.w;
    float lp = ps.x + ps.y + ps.z + ps.w;
    float lg = mg.x + mg.y + mg.z + mg.w;

    float a;
    float* acc = ws + OFF_ACC;
    a = blockSum(li, sm); if (threadIdx.x == 0) atomicAdd(acc + 0 + b, a);
    a = blockSum(lp, sm); if (threadIdx.x == 0) atomicAdd(acc + 2 + b, a);
    a = blockSum(lg, sm); if (threadIdx.x == 0) atomicAdd(acc + 4 + b, a);
}

// ---- depth loss partials
__global__ __launch_bounds__(256) void k_depth(const float* __restrict__ pd,
                                               const float* __restrict__ gd,
                                               const float* __restrict__ mk,
                                               float* ws) {
    __shared__ float sm[4];
    int b = blockIdx.x >> 8;
    int chunk = (blockIdx.x & 255) * 1024;
    const float* pb = pd + b * DPIX;
    const float* gb = gd + b * DPIX;
    const float* mb = mk + b * DPIX;
    float sg = 0, sg2 = 0, gx = 0, gy = 0, num = 0, den = 0;
    #pragma unroll
    for (int k = 0; k < 4; ++k) {
        int idx = chunk + k*256 + threadIdx.x;
        int h = idx >> 9;
        int w = idx & 511;
        float p = pb[idx], g = gb[idx], m = mb[idx];
        float lgv = logf(p + 0.1f) - logf(g + 0.1f);
        sg += lgv; sg2 += lgv * lgv;
        if (h < DHH - 1) {
            float p2 = pb[idx + DWW], g2 = gb[idx + DWW];
            gx += fabsf(fabsf(p - p2) - fabsf(g - g2));
        }
        if (w < DWW - 1) {
            float p2 = pb[idx + 1], g2 = gb[idx + 1];
            gy += fabsf(fabsf(p - p2) - fabsf(g - g2));
        }
        num += fabsf(p - g) * m;
        den += m;
    }
    float a;
    float* acc = ws + OFF_ACC;
    a = blockSum(sg,  sm); if (threadIdx.x == 0) atomicAdd(acc + 6 + b, a);
    a = blockSum(sg2, sm); if (threadIdx.x == 0) atomicAdd(acc + 8 + b, a);
    a = blockSum(gx,  sm); if (threadIdx.x == 0) atomicAdd(acc + 10, a);
    a = blockSum(gy,  sm); if (threadIdx.x == 0) atomicAdd(acc + 11, a);
    a = blockSum(num, sm); if (threadIdx.x == 0) atomicAdd(acc + 12, a);
    a = blockSum(den, sm); if (threadIdx.x == 0) atomicAdd(acc + 13, a);
}

// ---- parallel reduction of the two min arrays -> acc[14], acc[15]
__global__ __launch_bounds__(256) void k_redmin(float* ws) {
    __shared__ float sm[4];
    const float* mins = ws + OFF_MIN_P;   // 2*NPTS contiguous
    float s1 = 0.f, s2 = 0.f;
    #pragma unroll
    for (int k = 0; k < 4; ++k) {
        int idx = k * 8192 + blockIdx.x * 256 + threadIdx.x;  // [0, 32768)
        float v = mins[idx];
        if (idx < NPTS) s1 += v; else s2 += v;
    }
    float a;
    a = blockSum(s1, sm); if (threadIdx.x == 0) atomicAdd(ws + OFF_ACC + 14, a);
    a = blockSum(s2, sm); if (threadIdx.x == 0) atomicAdd(ws + OFF_ACC + 15, a);
}

// ---- finalize: combine all terms, write scalar
__global__ __launch_bounds__(64) void k_final(const float* ws, const int* iter,
                                              float* out) {
    if (threadIdx.x != 0) return;
    const float* acc = ws + OFF_ACC;
    float chamfer = acc[14] / (float)NPTS + acc[15] / (float)NPTS;
    float dsum = 0.f;
    for (int b = 0; b < 2; ++b)
        dsum += (2.f * acc[0+b] + 1e-5f) / (acc[2+b] + acc[4+b] + 1e-5f);
    float cldice = 1.f - 0.5f * dsum;
    float silog = 0.f;
    for (int b = 0; b < 2; ++b) {
        float gm = acc[6+b] / (float)DPIX;
        float gv = acc[8+b] / (float)DPIX - gm * gm;
        silog += 10.f * 0.5f * gv + 10.f * 0.5f * gm * gm;
    }
    float grad_l1 = acc[10] / (float)(B*(DHH-1)*DWW)
                  + acc[11] / (float)(B*DHH*(DWW-1));
    float mask_l1 = acc[12] / (acc[13] + 1e-8f);
    float dloss = silog + grad_l1 + mask_l1;
    int it = iter[0]; if (it < 1) it = 1;
    float gamma1 = 2.f * logf((float)it / 20000.f);
    out[0] = gamma1 * chamfer + 0.5f * cldice + 0.01f * dloss;
}

extern "C" void kernel_launch(void* const* d_in, const int* in_sizes, int n_in,
                              void* d_out, int out_size, void* d_ws, size_t ws_size,
                              hipStream_t stream) {
    const float* pc  = (const float*)d_in[0];
    const float* pv  = (const float*)d_in[1];
    const float* pd  = (const float*)d_in[2];
    const float* gp  = (const float*)d_in[3];
    const float* gvv = (const float*)d_in[4];
    const float* gd  = (const float*)d_in[5];
    const float* mk  = (const float*)d_in[6];
    const int*   it  = (const int*)d_in[7];
    float* ws  = (float*)d_ws;
    float* out = (float*)d_out;

    k_init_pack<<<128,  256, 0, stream>>>(pc, gp, ws);
    k_chamfer  <<<512,  256, 0, stream>>>(ws);
    k_erodeA   <<<2048, 256, 0, stream>>>(pv, gvv, ws);
    k_erodeB   <<<2048, 256, 0, stream>>>(ws);
    k_depth    <<<512,  256, 0, stream>>>(pd, gd, mk, ws);
    k_redmin   <<<32,   256, 0, stream>>>(ws);
    k_final    <<<1,    64,  0, stream>>>(ws, it, out);
}

// Round 4
// 144.214 us; speedup vs baseline: 1.6997x; 1.6997x over previous
//
#include <hip/hip_runtime.h>
#include <math.h>

// Problem constants
#define B 2
#define N 8192
#define M 8192
#define NPTS (B*N)
#define VD 64
#define VH 128
#define VW 128
#define VVOX (VD*VH*VW)         // 1048576 voxels per batch
#define DHH 512
#define DWW 512
#define DPIX (DHH*DWW)

// Workspace layout (float indices). NO atomics anywhere: all reductions are
// per-block partial stores to distinct addresses + later parallel reduce.
#define OFF_PACK_P 0                        // 16384 float4
#define OFF_PACK_G 65536                    // 16384 float4
#define OFF_WH_P   131072                   // B*VVOX floats, (w,h)-eroded pred
#define OFF_WH_G   2228224                  // B*VVOX floats, (w,h)-eroded gt
#define OFF_CHPART 4325376                  // [2 dirs][32 segs][16384 q] partial mins
#define OFF_PCL    5373952                  // [3 terms][512 blk] cldice partials
#define OFF_PDE    5375488                  // [6 terms][256 blk] depth partials
#define OFF_PCH    5377024                  // [64] chamfer block partial sums

__device__ __forceinline__ float blockSum(float v, volatile float* sm) {
    #pragma unroll
    for (int o = 32; o > 0; o >>= 1) v += __shfl_down(v, o, 64);
    int lane = threadIdx.x & 63, wid = threadIdx.x >> 6;
    __syncthreads();
    if (lane == 0) sm[wid] = v;
    __syncthreads();
    return sm[0] + sm[1] + sm[2] + sm[3];
}

__device__ __forceinline__ float min3f(float a, float b, float c) {
    return fminf(a, fminf(b, c));
}

// ---- pack points as (x,y,z,|.|^2) float4
__global__ __launch_bounds__(256) void k_pack(const float* __restrict__ pc,
                                              const float* __restrict__ gp,
                                              float* ws) {
    int i = blockIdx.x * 256 + threadIdx.x;
    if (i >= NPTS) return;
    float x = pc[3*i], y = pc[3*i+1], z = pc[3*i+2];
    ((float4*)(ws + OFF_PACK_P))[i] = make_float4(x, y, z, x*x + y*y + z*z);
    x = gp[3*i]; y = gp[3*i+1]; z = gp[3*i+2];
    ((float4*)(ws + OFF_PACK_G))[i] = make_float4(x, y, z, x*x + y*y + z*z);
}

// ---- chamfer: 8 queries/thread, targets in LDS; partial mins STORED (no atomics)
#define QT 8
#define SEGS 32
#define TSEG (M/SEGS)   // 256 targets/block
__global__ __launch_bounds__(256) void k_chamfer(float* ws) {
    __shared__ float4 tt[TSEG];
    const float4* packP = (const float4*)(ws + OFF_PACK_P);
    const float4* packG = (const float4*)(ws + OFF_PACK_G);
    unsigned int bid = blockIdx.x;
    int dir  = bid >> 8;
    int rem  = bid & 255;
    int seg  = rem >> 3;
    int qblk = rem & 7;
    const float4* Q = dir ? packG : packP;
    const float4* T = dir ? packP : packG;

    int qbase = qblk * (256*QT);     // 2048-query chunk, batch-aligned
    int b = qbase >> 13;

    tt[threadIdx.x] = T[b*M + seg*TSEG + threadIdx.x];

    float nx[QT], ny[QT], nz[QT], q2[QT], dmin[QT];
    #pragma unroll
    for (int k = 0; k < QT; ++k) {
        float4 qv = Q[qbase + k*256 + threadIdx.x];
        nx[k] = -2.f*qv.x; ny[k] = -2.f*qv.y; nz[k] = -2.f*qv.z;
        q2[k] = qv.w; dmin[k] = INFINITY;
    }
    __syncthreads();

    #pragma unroll 4
    for (int j = 0; j < TSEG; ++j) {
        float4 tv = tt[j];
        #pragma unroll
        for (int k = 0; k < QT; ++k) {
            float d = fmaf(tv.x, nx[k], fmaf(tv.y, ny[k], fmaf(tv.z, nz[k], tv.w)));
            dmin[k] = fminf(dmin[k], d);
        }
    }
    float* part = ws + OFF_CHPART + dir*(SEGS*NPTS) + seg*NPTS + qbase;
    #pragma unroll
    for (int k = 0; k < QT; ++k)
        part[k*256 + threadIdx.x] = dmin[k] + q2[k];
}

// ---- reduce chamfer partials: min over 32 segs per query, sum -> 64 partials
__global__ __launch_bounds__(256) void k_redmin(float* ws) {
    __shared__ float sm[4];
    int r   = blockIdx.x;          // 0..63
    int dir = r >> 5;
    int blk = r & 31;              // 512 queries per block
    const float* base = ws + OFF_CHPART + dir*(SEGS*NPTS) + blk*512;
    float s = 0.f;
    #pragma unroll
    for (int u = 0; u < 2; ++u) {
        int t = u*256 + threadIdx.x;
        float m = INFINITY;
        #pragma unroll
        for (int sg = 0; sg < SEGS; ++sg) m = fminf(m, base[sg*NPTS + t]);
        s += m;
    }
    float a = blockSum(s, sm);
    if (threadIdx.x == 0) ws[OFF_PCH + r] = a;
}

// ---- erodeA: separable (w,h) 3x3 min for BOTH volumes. 2048 blocks, 8 rows each.
__global__ __launch_bounds__(256) void k_erodeA(const float* __restrict__ pv,
                                                const float* __restrict__ gv,
                                                float* ws) {
    int r0 = blockIdx.x * 8 + (threadIdx.x >> 5);  // global row
    int q  = threadIdx.x & 31;
    int w  = q * 4;
    int b  = r0 >> 13;
    int rb = r0 & 8191;
    int d  = rb >> 7;
    int h  = rb & 127;
    int rowOff = b*VVOX + d*(VH*VW) + h*VW;
    int up = (h > 0)   ? -VW : 0;
    int dn = (h < 127) ?  VW : 0;

    float4 om[2];
    const float* vols[2] = {pv, gv};
    #pragma unroll
    for (int a = 0; a < 2; ++a) {
        const float* row = vols[a] + rowOff;
        float4 acc = make_float4(INFINITY, INFINITY, INFINITY, INFINITY);
        #pragma unroll
        for (int rr = 0; rr < 3; ++rr) {
            const float* rw = row + (rr == 0 ? up : (rr == 2 ? dn : 0));
            float4 c = *(const float4*)(rw + w);
            float l = (q > 0)  ? rw[w-1] : c.x;
            float r = (q < 31) ? rw[w+4] : c.w;
            acc.x = fminf(acc.x, min3f(l,   c.x, c.y));
            acc.y = fminf(acc.y, min3f(c.x, c.y, c.z));
            acc.z = fminf(acc.z, min3f(c.y, c.z, c.w));
            acc.w = fminf(acc.w, min3f(c.z, c.w, r));
        }
        om[a] = acc;
    }
    ((float4*)(ws + OFF_WH_P + rowOff))[q] = om[0];
    ((float4*)(ws + OFF_WH_G + rowOff))[q] = om[1];
}

// ---- erodeB: d-min + sigmoid + clDice partial sums. 512 blocks, 4 f4/thread.
__global__ __launch_bounds__(256) void k_erodeB(float* ws) {
    __shared__ float sm[4];
    const float4* whP = (const float4*)(ws + OFF_WH_P);
    const float4* whG = (const float4*)(ws + OFF_WH_G);
    int b   = blockIdx.x >> 8;          // batch, uniform per block
    int blk = blockIdx.x & 255;
    float li = 0.f, lp = 0.f, lg = 0.f;
    #pragma unroll
    for (int k = 0; k < 4; ++k) {
        int f4 = b*(VVOX/4) + (blk*4 + k)*256 + threadIdx.x;
        int d  = (f4 >> 12) & 63;       // 4096 float4 per d-plane; uniform per chunk
        int up = (d > 0)  ? -4096 : 0;
        int dn = (d < 63) ?  4096 : 0;
        float4 p0 = whP[f4+up], p1 = whP[f4], p2 = whP[f4+dn];
        float4 g0 = whG[f4+up], g1 = whG[f4], g2 = whG[f4+dn];
        float4 mp = make_float4(min3f(p0.x,p1.x,p2.x), min3f(p0.y,p1.y,p2.y),
                                min3f(p0.z,p1.z,p2.z), min3f(p0.w,p1.w,p2.w));
        float4 mg = make_float4(min3f(g0.x,g1.x,g2.x), min3f(g0.y,g1.y,g2.y),
                                min3f(g0.z,g1.z,g2.z), min3f(g0.w,g1.w,g2.w));
        float4 ps = make_float4(1.f/(1.f+__expf(-mp.x)), 1.f/(1.f+__expf(-mp.y)),
                                1.f/(1.f+__expf(-mp.z)), 1.f/(1.f+__expf(-mp.w)));
        li += ps.x*mg.x + ps.y*mg.y + ps.z*mg.z + ps.w*mg.w;
        lp += ps.x + ps.y + ps.z + ps.w;
        lg += mg.x + mg.y + mg.z + mg.w;
    }
    float a;
    float* part = ws + OFF_PCL;         // [3][512]
    a = blockSum(li, sm); if (threadIdx.x == 0) part[          blockIdx.x] = a;
    a = blockSum(lp, sm); if (threadIdx.x == 0) part[512     + blockIdx.x] = a;
    a = blockSum(lg, sm); if (threadIdx.x == 0) part[1024    + blockIdx.x] = a;
}

// ---- depth loss partials: 256 blocks (128/batch), 2048 px/block
__global__ __launch_bounds__(256) void k_depth(const float* __restrict__ pd,
                                               const float* __restrict__ gd,
                                               const float* __restrict__ mk,
                                               float* ws) {
    __shared__ float sm[4];
    int b   = blockIdx.x >> 7;
    int blk = blockIdx.x & 127;
    const float* pb = pd + b * DPIX;
    const float* gb = gd + b * DPIX;
    const float* mb = mk + b * DPIX;
    float sg = 0, sg2 = 0, gx = 0, gy = 0, num = 0, den = 0;
    #pragma unroll
    for (int k = 0; k < 8; ++k) {
        int idx = (blk*8 + k)*256 + threadIdx.x;   // [0, DPIX)
        int h = idx >> 9;
        int w = idx & 511;
        float p = pb[idx], g = gb[idx], m = mb[idx];
        float lgv = logf(p + 0.1f) - logf(g + 0.1f);
        sg += lgv; sg2 += lgv * lgv;
        if (h < DHH - 1) {
            float p2 = pb[idx + DWW], g2 = gb[idx + DWW];
            gx += fabsf(fabsf(p - p2) - fabsf(g - g2));
        }
        if (w < DWW - 1) {
            float p2 = pb[idx + 1], g2 = gb[idx + 1];
            gy += fabsf(fabsf(p - p2) - fabsf(g - g2));
        }
        num += fabsf(p - g) * m;
        den += m;
    }
    float a;
    float* part = ws + OFF_PDE;         // [6][256]
    a = blockSum(sg,  sm); if (threadIdx.x == 0) part[       blockIdx.x] = a;
    a = blockSum(sg2, sm); if (threadIdx.x == 0) part[256  + blockIdx.x] = a;
    a = blockSum(gx,  sm); if (threadIdx.x == 0) part[512  + blockIdx.x] = a;
    a = blockSum(gy,  sm); if (threadIdx.x == 0) part[768  + blockIdx.x] = a;
    a = blockSum(num, sm); if (threadIdx.x == 0) part[1024 + blockIdx.x] = a;
    a = blockSum(den, sm); if (threadIdx.x == 0) part[1280 + blockIdx.x] = a;
}

__device__ __forceinline__ float sumRange(const float* p, int n, volatile float* sm) {
    float s = 0.f;
    for (int t = threadIdx.x; t < n; t += 256) s += p[t];
    return blockSum(s, sm);
}

// ---- finalize: reduce all partial arrays, combine, write scalar
__global__ __launch_bounds__(256) void k_final(const float* ws, const int* iter,
                                               float* out) {
    __shared__ float sm[4];
    float sch = sumRange(ws + OFF_PCH, 64, sm);                 // both dirs
    float i0  = sumRange(ws + OFF_PCL,        256, sm);
    float i1  = sumRange(ws + OFF_PCL + 256,  256, sm);
    float p0  = sumRange(ws + OFF_PCL + 512,  256, sm);
    float p1  = sumRange(ws + OFF_PCL + 768,  256, sm);
    float g0  = sumRange(ws + OFF_PCL + 1024, 256, sm);
    float g1  = sumRange(ws + OFF_PCL + 1280, 256, sm);
    float sg0 = sumRange(ws + OFF_PDE,        128, sm);
    float sg1 = sumRange(ws + OFF_PDE + 128,  128, sm);
    float s20 = sumRange(ws + OFF_PDE + 256,  128, sm);
    float s21 = sumRange(ws + OFF_PDE + 384,  128, sm);
    float gx  = sumRange(ws + OFF_PDE + 512,  256, sm);
    float gy  = sumRange(ws + OFF_PDE + 768,  256, sm);
    float num = sumRange(ws + OFF_PDE + 1024, 256, sm);
    float den = sumRange(ws + OFF_PDE + 1280, 256, sm);
    if (threadIdx.x != 0) return;

    float chamfer = sch / (float)NPTS;      // (sum_minP + sum_minG)/NPTS
    float dsum = (2.f*i0 + 1e-5f) / (p0 + g0 + 1e-5f)
               + (2.f*i1 + 1e-5f) / (p1 + g1 + 1e-5f);
    float cldice = 1.f - 0.5f * dsum;
    float silog = 0.f;
    {
        float gm = sg0 / (float)DPIX;
        float gv = s20 / (float)DPIX - gm*gm;
        silog += 10.f*0.5f*gv + 10.f*0.5f*gm*gm;
        gm = sg1 / (float)DPIX;
        gv = s21 / (float)DPIX - gm*gm;
        silog += 10.f*0.5f*gv + 10.f*0.5f*gm*gm;
    }
    float grad_l1 = gx / (float)(B*(DHH-1)*DWW) + gy / (float)(B*DHH*(DWW-1));
    float mask_l1 = num / (den + 1e-8f);
    float dloss = silog + grad_l1 + mask_l1;
    int it = iter[0]; if (it < 1) it = 1;
    float gamma1 = 2.f * logf((float)it / 20000.f);
    out[0] = gamma1 * chamfer + 0.5f * cldice + 0.01f * dloss;
}

extern "C" void kernel_launch(void* const* d_in, const int* in_sizes, int n_in,
                              void* d_out, int out_size, void* d_ws, size_t ws_size,
                              hipStream_t stream) {
    const float* pc  = (const float*)d_in[0];
    const float* pv  = (const float*)d_in[1];
    const float* pd  = (const float*)d_in[2];
    const float* gp  = (const float*)d_in[3];
    const float* gvv = (const float*)d_in[4];
    const float* gd  = (const float*)d_in[5];
    const float* mk  = (const float*)d_in[6];
    const int*   it  = (const int*)d_in[7];
    float* ws  = (float*)d_ws;
    float* out = (float*)d_out;

    k_pack   <<<64,   256, 0, stream>>>(pc, gp, ws);
    k_chamfer<<<512,  256, 0, stream>>>(ws);
    k_redmin <<<64,   256, 0, stream>>>(ws);
    k_erodeA <<<2048, 256, 0, stream>>>(pv, gvv, ws);
    k_erodeB <<<512,  256, 0, stream>>>(ws);
    k_depth  <<<256,  256, 0, stream>>>(pd, gd, mk, ws);
    k_final  <<<1,    256, 0, stream>>>(ws, it, out);
}